// Round 3
// baseline (369.833 us; speedup 1.0000x reference)
//
#include <hip/hip_runtime.h>

// Problem: B=32, CI=64, CO=64, H=128, W=128, E=5, T=10, 5x5 SAME conv (MoDE).
// d_out = y[32*64*128*128] f32 ++ task_id[32] (as float).
//
// ws layout:
//   xt : [32 b][132 hp][8 cc][132 wp][8 ci] bf16 = 71,368,704 B
//        hp = h+2 (rows 0,1,130,131 zero), wp = w+2 (borders zero)
//   wk : [10 t][25 tap][64 co][64 ci] bf16       =  2,048,000 B
// requires ws_size >= 73,416,704 bytes.
#define WK_OFFSET_BYTES 71368704ull

using bf16x8   = __attribute__((ext_vector_type(8)))  __bf16;
using floatx16 = __attribute__((ext_vector_type(16))) float;

static __device__ __forceinline__ unsigned short f2bf(float f) {
    unsigned int u = __float_as_uint(f);
    u += 0x7FFFu + ((u >> 16) & 1u);          // round-to-nearest-even (finite inputs)
    return (unsigned short)(u >> 16);
}

static __device__ __forceinline__ floatx16 mfma16(bf16x8 a, bf16x8 b, floatx16 c) {
    return __builtin_amdgcn_mfma_f32_32x32x16_bf16(a, b, c, 0, 0, 0);
}

// async global->LDS DMA, 16B per lane. LDS dest = wave-uniform base + lane*16
// (our per-lane lds pointers are consecutive, so first-lane base is correct).
static __device__ __forceinline__ void gload_lds16(const void* g, void* l) {
    __builtin_amdgcn_global_load_lds(
        (const __attribute__((address_space(1))) void*)g,
        (__attribute__((address_space(3))) void*)l, 16, 0, 0);
}

// ---------------------------------------------------------------------------
// Kernel 1 (fused): blocks 0..4223  = transform x -> xt (32 b x 132 padded rows)
//                   blocks 4224..4383 = gate softmax + per-task kernel synthesis
// ---------------------------------------------------------------------------
__global__ __launch_bounds__(256) void pre_kernel(
    const float* __restrict__ x,
    const float* __restrict__ gate_w, const float* __restrict__ gate_b,
    const float* __restrict__ w5, const float* __restrict__ w3,
    const float* __restrict__ w1, const float* __restrict__ wavg3,
    const float* __restrict__ wavg5, const int* __restrict__ task_id,
    unsigned short* __restrict__ xt, unsigned short* __restrict__ wk,
    float* __restrict__ out_task)
{
    const int blk = blockIdx.x;
    const int tid = threadIdx.x;
    __shared__ float g[5][64];

    if (blk < 4224) {
        // -------- transform: one padded row (b, hp) per block --------
        const int b  = blk / 132;
        const int hp = blk - b * 132;
        const int h  = hp - 2;
        const bool vrow = (h >= 0) && (h < 128);
        unsigned short* dst_row = xt + (size_t)blk * 8448;

        for (int i = tid; i < 1056; i += 256) {      // 8 cc * 132 wp uint4 blocks
            int cc = i / 132;
            int wp = i - cc * 132;
            unsigned int pk[4] = {0u, 0u, 0u, 0u};
            if (vrow && wp >= 2 && wp < 130) {
                const float* xp = x + (((size_t)(b * 64 + cc * 8) * 128 + h) * 128 + (wp - 2));
                #pragma unroll
                for (int j = 0; j < 4; ++j) {
                    unsigned short lo = f2bf(xp[(2 * j)     * 16384]);
                    unsigned short hi = f2bf(xp[(2 * j + 1) * 16384]);
                    pk[j] = (unsigned int)lo | ((unsigned int)hi << 16);
                }
            }
            *(uint4*)(dst_row + (size_t)i * 8) = make_uint4(pk[0], pk[1], pk[2], pk[3]);
        }
    } else {
        // -------- prep: per-task 5x5 kernel synthesis --------
        const int pb = blk - 4224;
        const int t = pb >> 4;          // 0..9
        const int chunk = pb & 15;      // 0..15

        if (tid < 64) {
            float l[5];
            float m = -1e30f;
            #pragma unroll
            for (int e = 0; e < 5; ++e) {
                l[e] = gate_w[(e * 64 + tid) * 10 + t] + gate_b[e * 64 + tid];
                m = fmaxf(m, l[e]);
            }
            float s = 0.f;
            #pragma unroll
            for (int e = 0; e < 5; ++e) { l[e] = expf(l[e] - m); s += l[e]; }
            float inv = 1.f / s;
            #pragma unroll
            for (int e = 0; e < 5; ++e) g[e][tid] = l[e] * inv;
        }
        __syncthreads();

        for (int it = 0; it < 25; ++it) {
            int idx = chunk * 6400 + it * 256 + tid;
            int ci  = idx & 63;
            int o   = (idx >> 6) & 63;
            int tap = idx >> 12;               // 0..24
            int ky = tap / 5, kx = tap - ky * 5;

            float v = g[0][o] * w5[(o * 64 + ci) * 25 + tap];
            bool in3 = (ky >= 1 && ky <= 3 && kx >= 1 && kx <= 3);
            if (in3) {
                v += g[1][o] * w3[(o * 64 + ci) * 9 + (ky - 1) * 3 + (kx - 1)];
                v += g[3][o] * wavg3[o * 64 + ci] * (1.f / 9.f);
            }
            if (ky == 2 && kx == 2) v += g[2][o] * w1[o * 64 + ci];
            v += g[4][o] * wavg5[o * 64 + ci] * (1.f / 25.f);

            wk[(t * 25 + tap) * 4096 + o * 64 + ci] = f2bf(v);
        }

        if (pb == 0 && tid < 32) out_task[tid] = (float)task_id[tid];
    }
}

// ---------------------------------------------------------------------------
// Kernel 2: MFMA conv, 2 blocks/CU for inter-block overlap.
// Block = 256 thr (4 waves), tile = 64co x (4 rows x 128 w); wave = 4r x 32w.
// LDS = input only: 2 x (8 rows x [2cc][132wp][8ci]) = 67,584 B -> 2 blocks/CU,
// so block A's prologue fetch + epilogue store burst overlap block B's MFMAs.
// Weights (A-frags) are read directly from global per kx (L1/L2-cached; all
// waves on a CU read the same ~8 KB per tap column). ky-reuse decomposition:
// one B ds_read feeds up to 8 MFMAs; per wave per q: 40 B ds_read + 50 A
// global loads vs 200 MFMA.
// vmcnt ordering: stage_i(q+1) issues BEFORE the kx loop's A loads, so A-load
// consumption in-order-retires the DMA during compute; the per-q vmcnt(0)
// drains a transfer that finished a full compute phase ago (~free).
// grid = 1024 (32 b * 32 htiles), XCD-swizzled: each XCD owns 4 whole images.
// ---------------------------------------------------------------------------
__global__ __launch_bounds__(256, 2) void conv_kernel(
    const unsigned short* __restrict__ xt, const unsigned short* __restrict__ wk,
    const int* __restrict__ task_id, float* __restrict__ out)
{
    __shared__ unsigned short ibuf[2][16896];   // 2 x 33,792 B

    // XCD swizzle (1024 = 8*128, bijective): XCD k gets blocks k*128..k*128+127
    const int blk = ((blockIdx.x & 7) << 7) | (blockIdx.x >> 3);
    const int b  = blk >> 5;
    const int ht = blk & 31;
    const int t  = task_id[b];

    const int tid  = threadIdx.x;
    const int lane = tid & 63;
    const int wc   = tid >> 6;             // wave 0..3 -> w column (32 outputs)
    const int lane31 = lane & 31;
    const int laneh  = lane >> 5;

    floatx16 acc[4][2];                    // [out row o][co half]
    #pragma unroll
    for (int o = 0; o < 4; ++o)
        #pragma unroll
        for (int c = 0; c < 2; ++c)
            #pragma unroll
            for (int r = 0; r < 16; ++r) acc[o][c][r] = 0.f;

    const unsigned short* wkt = wk + t * 102400;           // [25][64 co][64 ci]
    const size_t ibase0 = ((size_t)(b * 132 + ht * 4)) * 8448;

    // stage 8 input rows (padded hp = ht*4 .. +7), ci-quarter q -> ibuf[s]
    auto stage_i = [&](int s, int q) {
        const unsigned short* gsrc = xt + ibase0 + q * 2112;
        unsigned short* ldst = &ibuf[s][0];
        #pragma unroll
        for (int j = 0; j < 8; ++j) {          // 2112 uint4 = 256*8 + 64
            int i = j * 256 + tid;
            int r = i / 264;
            int rem = i - r * 264;
            gload_lds16(gsrc + (size_t)r * 8448 + rem * 8, ldst + i * 8);
        }
        if (tid < 64) {
            int i = 2048 + tid;
            int r = i / 264;
            int rem = i - r * 264;
            gload_lds16(gsrc + (size_t)r * 8448 + rem * 8, ldst + i * 8);
        }
    };

    // prologue
    stage_i(0, 0);
    asm volatile("s_waitcnt vmcnt(0)" ::: "memory");
    __builtin_amdgcn_s_barrier();
    __builtin_amdgcn_sched_barrier(0);

    for (int q = 0; q < 4; ++q) {
        const int s = q & 1;
        if (q < 3) stage_i(s ^ 1, q + 1);      // in flight during compute below

        const unsigned short* ib = &ibuf[s][0];
        const unsigned short* wq = wkt + q * 16 + laneh * 8;
        __builtin_amdgcn_s_setprio(1);
        #pragma unroll
        for (int kx = 0; kx < 5; ++kx) {
            // A fragments for this kx: 5 ky x 2 co-halves, direct from L1/L2
            bf16x8 aF[5][2];
            #pragma unroll
            for (int ky = 0; ky < 5; ++ky) {
                const unsigned short* ap = wq + (ky * 5 + kx) * 4096 + lane31 * 64;
                aF[ky][0] = *(const bf16x8*)(ap);
                aF[ky][1] = *(const bf16x8*)(ap + 2048);   // +32 co
            }
            // one B ds_read per staged input row feeds up to 8 MFMAs
            #pragma unroll
            for (int hr = 0; hr < 8; ++hr) {
                bf16x8 bb = *(const bf16x8*)(ib + hr * 2112 + laneh * 1056
                                             + (wc * 32 + lane31 + kx) * 8);
                #pragma unroll
                for (int ky = 0; ky < 5; ++ky) {
                    const int o = hr - ky;     // compile-time after unroll
                    if (o >= 0 && o < 4) {
                        acc[o][0] = mfma16(aF[ky][0], bb, acc[o][0]);
                        acc[o][1] = mfma16(aF[ky][1], bb, acc[o][1]);
                    }
                }
            }
        }
        __builtin_amdgcn_s_setprio(0);

        if (q < 3) {
            // DMA for q+1 completed long ago (issued before this q's compute);
            // barrier protects ibuf[s] before q+2's overwrite.
            asm volatile("s_waitcnt vmcnt(0) lgkmcnt(0)" ::: "memory");
            __builtin_amdgcn_s_barrier();
            __builtin_amdgcn_sched_barrier(0);
        }
    }

    // Epilogue: C/D layout (32x32): col(w) = lane&31, row(co) = (reg&3)+8*(reg>>2)+4*(lane>>5)
    #pragma unroll
    for (int o = 0; o < 4; ++o) {
        const int h = ht * 4 + o;
        #pragma unroll
        for (int c = 0; c < 2; ++c) {
            const int w = wc * 32 + lane31;
            #pragma unroll
            for (int reg = 0; reg < 16; ++reg) {
                int co = c * 32 + (reg & 3) + 8 * (reg >> 2) + 4 * laneh;
                out[((size_t)(b * 64 + co) * 128 + h) * 128 + w] = acc[o][c][reg];
            }
        }
    }
}

// ---------------------------------------------------------------------------
extern "C" void kernel_launch(void* const* d_in, const int* in_sizes, int n_in,
                              void* d_out, int out_size, void* d_ws, size_t ws_size,
                              hipStream_t stream) {
    const float* x       = (const float*)d_in[0];
    const int*   task_id = (const int*)  d_in[1];
    const float* gate_w  = (const float*)d_in[2];
    const float* gate_b  = (const float*)d_in[3];
    const float* w5      = (const float*)d_in[4];
    const float* w3      = (const float*)d_in[5];
    const float* w1      = (const float*)d_in[6];
    const float* wavg3   = (const float*)d_in[7];
    const float* wavg5   = (const float*)d_in[8];

    float* out = (float*)d_out;
    float* out_task = out + 32 * 64 * 128 * 128;   // second tuple element

    unsigned short* xt = (unsigned short*)d_ws;
    unsigned short* wk = (unsigned short*)((char*)d_ws + WK_OFFSET_BYTES);
    // requires ws_size >= 73,416,704 bytes

    pre_kernel<<<dim3(4384), dim3(256), 0, stream>>>(
        x, gate_w, gate_b, w5, w3, w1, wavg3, wavg5, task_id, xt, wk, out_task);
    conv_kernel<<<dim3(1024), dim3(256), 0, stream>>>(xt, wk, task_id, out);
}

// Round 5
// 364.840 us; speedup vs baseline: 1.0137x; 1.0137x over previous
//
#include <hip/hip_runtime.h>

// Problem: B=32, CI=64, CO=64, H=128, W=128, E=5, T=10, 5x5 SAME conv (MoDE).
// d_out = y[32*64*128*128] f32 ++ task_id[32] (as float).
//
// ws layout:
//   xt : [32 b][132 hp][8 cc][132 wp][8 ci] bf16 = 71,368,704 B
//        hp = h+2 (rows 0,1,130,131 zero), wp = w+2 (borders zero)
//   wk : [10 t][25 tap][64 co][64 ci] bf16       =  2,048,000 B
// requires ws_size >= 73,416,704 bytes.
#define WK_OFFSET_BYTES 71368704ull

using bf16x8   = __attribute__((ext_vector_type(8)))  __bf16;
using floatx16 = __attribute__((ext_vector_type(16))) float;

static __device__ __forceinline__ unsigned short f2bf(float f) {
    unsigned int u = __float_as_uint(f);
    u += 0x7FFFu + ((u >> 16) & 1u);          // round-to-nearest-even (finite inputs)
    return (unsigned short)(u >> 16);
}

static __device__ __forceinline__ floatx16 mfma16(bf16x8 a, bf16x8 b, floatx16 c) {
    return __builtin_amdgcn_mfma_f32_32x32x16_bf16(a, b, c, 0, 0, 0);
}

// async global->LDS DMA, 16B per lane. LDS dest = wave-uniform base + lane*16
// (our per-lane lds pointers are consecutive, so first-lane base is correct).
static __device__ __forceinline__ void gload_lds16(const void* g, void* l) {
    __builtin_amdgcn_global_load_lds(
        (const __attribute__((address_space(1))) void*)g,
        (__attribute__((address_space(3))) void*)l, 16, 0, 0);
}

// ---------------------------------------------------------------------------
// Kernel 1 (fused): blocks 0..4223  = transform x -> xt (32 b x 132 padded rows)
//                   blocks 4224..4383 = gate softmax + per-task kernel synthesis
// ---------------------------------------------------------------------------
__global__ __launch_bounds__(256) void pre_kernel(
    const float* __restrict__ x,
    const float* __restrict__ gate_w, const float* __restrict__ gate_b,
    const float* __restrict__ w5, const float* __restrict__ w3,
    const float* __restrict__ w1, const float* __restrict__ wavg3,
    const float* __restrict__ wavg5, const int* __restrict__ task_id,
    unsigned short* __restrict__ xt, unsigned short* __restrict__ wk,
    float* __restrict__ out_task)
{
    const int blk = blockIdx.x;
    const int tid = threadIdx.x;
    __shared__ float g[5][64];

    if (blk < 4224) {
        // -------- transform: one padded row (b, hp) per block --------
        const int b  = blk / 132;
        const int hp = blk - b * 132;
        const int h  = hp - 2;
        const bool vrow = (h >= 0) && (h < 128);
        unsigned short* dst_row = xt + (size_t)blk * 8448;

        for (int i = tid; i < 1056; i += 256) {      // 8 cc * 132 wp uint4 blocks
            int cc = i / 132;
            int wp = i - cc * 132;
            unsigned int pk[4] = {0u, 0u, 0u, 0u};
            if (vrow && wp >= 2 && wp < 130) {
                const float* xp = x + (((size_t)(b * 64 + cc * 8) * 128 + h) * 128 + (wp - 2));
                #pragma unroll
                for (int j = 0; j < 4; ++j) {
                    unsigned short lo = f2bf(xp[(2 * j)     * 16384]);
                    unsigned short hi = f2bf(xp[(2 * j + 1) * 16384]);
                    pk[j] = (unsigned int)lo | ((unsigned int)hi << 16);
                }
            }
            *(uint4*)(dst_row + (size_t)i * 8) = make_uint4(pk[0], pk[1], pk[2], pk[3]);
        }
    } else {
        // -------- prep: per-task 5x5 kernel synthesis --------
        const int pb = blk - 4224;
        const int t = pb >> 4;          // 0..9
        const int chunk = pb & 15;      // 0..15

        if (tid < 64) {
            float l[5];
            float m = -1e30f;
            #pragma unroll
            for (int e = 0; e < 5; ++e) {
                l[e] = gate_w[(e * 64 + tid) * 10 + t] + gate_b[e * 64 + tid];
                m = fmaxf(m, l[e]);
            }
            float s = 0.f;
            #pragma unroll
            for (int e = 0; e < 5; ++e) { l[e] = expf(l[e] - m); s += l[e]; }
            float inv = 1.f / s;
            #pragma unroll
            for (int e = 0; e < 5; ++e) g[e][tid] = l[e] * inv;
        }
        __syncthreads();

        for (int it = 0; it < 25; ++it) {
            int idx = chunk * 6400 + it * 256 + tid;
            int ci  = idx & 63;
            int o   = (idx >> 6) & 63;
            int tap = idx >> 12;               // 0..24
            int ky = tap / 5, kx = tap - ky * 5;

            float v = g[0][o] * w5[(o * 64 + ci) * 25 + tap];
            bool in3 = (ky >= 1 && ky <= 3 && kx >= 1 && kx <= 3);
            if (in3) {
                v += g[1][o] * w3[(o * 64 + ci) * 9 + (ky - 1) * 3 + (kx - 1)];
                v += g[3][o] * wavg3[o * 64 + ci] * (1.f / 9.f);
            }
            if (ky == 2 && kx == 2) v += g[2][o] * w1[o * 64 + ci];
            v += g[4][o] * wavg5[o * 64 + ci] * (1.f / 25.f);

            wk[(t * 25 + tap) * 4096 + o * 64 + ci] = f2bf(v);
        }

        if (pb == 0 && tid < 32) out_task[tid] = (float)task_id[tid];
    }
}

// ---------------------------------------------------------------------------
// Kernel 2: MFMA conv (R2 structure + wave desync + weight reg-prefetch).
// Block = 512 thr (8 waves), tile = 64co x (8 rows x 128 w).
// Wave = (row-group rg: 4 rows) x (w-col wc: 32 w) x 64 co -> acc[4][2].
// Per q (16-ci quarter):
//   input:  12 rows x [2 cc][132 wp][8 ci] = 50,688 B (double-buffered, DMA)
//   weights:[25 tap][2 cih][64 co][8 ci]   = 51,200 B (single-buffered)
// Anti-lockstep: each wave walks kx in a rotated order (kx0 = wave*3 % 5) so
// one wave's ds_read burst overlaps its SIMD-partner's MFMA run (the shared
// LDS pipe and matrix pipes stop serializing CU-wide).
// Weights for q+1 are prefetched to REGISTERS during compute(q) (T14) and
// ds_written to wlds between the two barriers - removes the exposed L2 fetch.
// Compute phase has no VMEM consumption, so all prefetch stays in flight.
// grid = 512 (32 b * 16 htiles), XCD-swizzled: each XCD owns 4 whole images.
// ---------------------------------------------------------------------------
__global__ __launch_bounds__(512, 2) void conv_kernel(
    const unsigned short* __restrict__ xt, const unsigned short* __restrict__ wk,
    const int* __restrict__ task_id, float* __restrict__ out)
{
    __shared__ unsigned short ibuf[2][25344];   // 2 x 50,688 B
    __shared__ unsigned short wlds[25600];      //     51,200 B   (total 149 KiB)

    // XCD swizzle (512 = 8*64, bijective): XCD k gets blocks k*64..k*64+63
    const int blk = ((blockIdx.x & 7) << 6) | (blockIdx.x >> 3);
    const int b  = blk >> 4;
    const int ht = blk & 15;
    const int t  = task_id[b];

    const int tid  = threadIdx.x;
    const int lane = tid & 63;
    const int wave = tid >> 6;
    const int rg = wave >> 2;              // row group 0..1 (4 output rows each)
    const int wc = wave & 3;               // w column 0..3 (32 outputs each)
    const int lane31 = lane & 31;
    const int laneh  = lane >> 5;
    const int kx0 = (wave * 3) % 5;        // per-wave kx rotation (desync)

    floatx16 acc[4][2];                    // [out row o][co half]
    #pragma unroll
    for (int o = 0; o < 4; ++o)
        #pragma unroll
        for (int c = 0; c < 2; ++c)
            #pragma unroll
            for (int r = 0; r < 16; ++r) acc[o][c][r] = 0.f;

    const unsigned short* wkt = wk + t * 102400;           // [25][64 co][64 ci]
    const size_t ibase0 = ((size_t)(b * 132 + ht * 8)) * 8448;

    // stage 12 input rows (padded hp = ht*8 .. +11), ci-quarter q -> ibuf[s]
    auto stage_i = [&](int s, int q) {
        const unsigned short* gsrc = xt + ibase0 + q * 2112;
        unsigned short* ldst = &ibuf[s][0];
        #pragma unroll
        for (int j = 0; j < 6; ++j) {          // 3168 uint4 = 512*6 + 96
            int i = j * 512 + tid;
            int r = i / 264;
            int rem = i - r * 264;
            gload_lds16(gsrc + (size_t)r * 8448 + rem * 8, ldst + i * 8);
        }
        if (tid < 96) {
            int i = 3072 + tid;
            int r = i / 264;
            int rem = i - r * 264;
            gload_lds16(gsrc + (size_t)r * 8448 + rem * 8, ldst + i * 8);
        }
    };
    // stage weights via DMA (prologue only), ci-quarter q -> wlds[tap][cih][co][8ci]
    auto stage_w_dma = [&](int q) {
        const unsigned short* gsrc = wkt + q * 16;
        unsigned short* ldst = &wlds[0];
        #pragma unroll
        for (int j = 0; j < 7; ++j) {          // 3200 uint4 = 512*6 + 128
            if (j < 6 || tid < 128) {
                int i = j * 512 + tid;
                int tap = i >> 7;
                int rem = i & 127;
                int cih = rem >> 6;
                int co  = rem & 63;
                gload_lds16(gsrc + tap * 4096 + co * 64 + cih * 8, ldst + i * 8);
            }
        }
    };

    // per-thread weight-load element offsets (constant across q)
    int woff[7];
    #pragma unroll
    for (int j = 0; j < 7; ++j) {
        int i = j * 512 + tid;
        int tap = i >> 7;
        int rem = i & 127;
        int cih = rem >> 6;
        int co  = rem & 63;
        woff[j] = tap * 4096 + co * 64 + cih * 8;
    }

    // prologue
    stage_w_dma(0);
    stage_i(0, 0);
    asm volatile("s_waitcnt vmcnt(0)" ::: "memory");
    __builtin_amdgcn_s_barrier();
    __builtin_amdgcn_sched_barrier(0);

    for (int q = 0; q < 4; ++q) {
        const int s = q & 1;
        uint4 wreg[7] = {};
        if (q < 3) {
            stage_i(s ^ 1, q + 1);             // DMA in flight during compute
            const unsigned short* wsrc = wkt + (q + 1) * 16;
            #pragma unroll
            for (int j = 0; j < 7; ++j)        // weights(q+1) -> regs, in flight
                if (j < 6 || tid < 128)
                    wreg[j] = *(const uint4*)(wsrc + woff[j]);
        }

        const unsigned short* ib = &ibuf[s][0];
        __builtin_amdgcn_s_setprio(1);
        #pragma unroll
        for (int kk = 0; kk < 5; ++kk) {
            int kx = kk + kx0; if (kx >= 5) kx -= 5;   // per-wave rotated order
            const unsigned short* wkx = wlds + kx * 1024 + laneh * 512 + lane31 * 8;
            const unsigned short* ibb = ib + laneh * 1056 + (wc * 32 + lane31 + kx) * 8;
            // A fragments for this kx: 5 ky x 2 co-halves
            bf16x8 aF[5][2];
            #pragma unroll
            for (int ky = 0; ky < 5; ++ky) {
                const unsigned short* ap = wkx + ky * 5120;   // tap = ky*5+kx
                aF[ky][0] = *(const bf16x8*)(ap);
                aF[ky][1] = *(const bf16x8*)(ap + 256);       // +32 co
            }
            // one B ds_read per staged input row feeds up to 8 MFMAs
            #pragma unroll
            for (int hr = 0; hr < 8; ++hr) {
                bf16x8 bb = *(const bf16x8*)(ibb + (rg * 4 + hr) * 2112);
                #pragma unroll
                for (int ky = 0; ky < 5; ++ky) {
                    const int o = hr - ky;     // compile-time after unroll
                    if (o >= 0 && o < 4) {
                        acc[o][0] = mfma16(aF[ky][0], bb, acc[o][0]);
                        acc[o][1] = mfma16(aF[ky][1], bb, acc[o][1]);
                    }
                }
            }
        }
        __builtin_amdgcn_s_setprio(0);

        asm volatile("s_waitcnt lgkmcnt(0)" ::: "memory");
        __builtin_amdgcn_s_barrier();          // #1: all waves done with wlds/ibuf[s]
        __builtin_amdgcn_sched_barrier(0);
        if (q < 3) {
            asm volatile("s_waitcnt vmcnt(0)" ::: "memory");  // wreg + stage_i landed (long ago)
            #pragma unroll
            for (int j = 0; j < 7; ++j)
                if (j < 6 || tid < 128)
                    *(uint4*)(wlds + (j * 512 + tid) * 8) = wreg[j];
            asm volatile("s_waitcnt lgkmcnt(0)" ::: "memory");
            __builtin_amdgcn_s_barrier();      // #2: wlds(q+1) visible
            __builtin_amdgcn_sched_barrier(0);
        }
    }

    // Epilogue: C/D layout (32x32): col(w) = lane&31, row(co) = (reg&3)+8*(reg>>2)+4*(lane>>5)
    #pragma unroll
    for (int o = 0; o < 4; ++o) {
        const int h = ht * 8 + rg * 4 + o;
        #pragma unroll
        for (int c = 0; c < 2; ++c) {
            const int w = wc * 32 + lane31;
            #pragma unroll
            for (int reg = 0; reg < 16; ++reg) {
                int co = c * 32 + (reg & 3) + 8 * (reg >> 2) + 4 * laneh;
                out[((size_t)(b * 64 + co) * 128 + h) * 128 + w] = acc[o][c][reg];
            }
        }
    }
}

// ---------------------------------------------------------------------------
extern "C" void kernel_launch(void* const* d_in, const int* in_sizes, int n_in,
                              void* d_out, int out_size, void* d_ws, size_t ws_size,
                              hipStream_t stream) {
    const float* x       = (const float*)d_in[0];
    const int*   task_id = (const int*)  d_in[1];
    const float* gate_w  = (const float*)d_in[2];
    const float* gate_b  = (const float*)d_in[3];
    const float* w5      = (const float*)d_in[4];
    const float* w3      = (const float*)d_in[5];
    const float* w1      = (const float*)d_in[6];
    const float* wavg3   = (const float*)d_in[7];
    const float* wavg5   = (const float*)d_in[8];

    float* out = (float*)d_out;
    float* out_task = out + 32 * 64 * 128 * 128;   // second tuple element

    unsigned short* xt = (unsigned short*)d_ws;
    unsigned short* wk = (unsigned short*)((char*)d_ws + WK_OFFSET_BYTES);
    // requires ws_size >= 73,416,704 bytes

    pre_kernel<<<dim3(4384), dim3(256), 0, stream>>>(
        x, gate_w, gate_b, w5, w3, w1, wavg3, wavg5, task_id, xt, wk, out_task);
    conv_kernel<<<dim3(512), dim3(512), 0, stream>>>(xt, wk, task_id, out);
}

// Round 6
// 343.445 us; speedup vs baseline: 1.0768x; 1.0623x over previous
//
#include <hip/hip_runtime.h>

// Problem: B=32, CI=64, CO=64, H=128, W=128, E=5, T=10, 5x5 SAME conv (MoDE).
// d_out = y[32*64*128*128] f32 ++ task_id[32] (as float).
//
// ws layout:
//   xt : [32 b][132 hp][8 cc][132 wp][8 ci] bf16 = 71,368,704 B
//        hp = h+2 (rows 0,1,130,131 zero), wp = w+2 (borders zero)
//   wk : [10 t][25 tap][64 co][64 ci] bf16       =  2,048,000 B
// requires ws_size >= 73,416,704 bytes.
#define WK_OFFSET_BYTES 71368704ull

using bf16x8   = __attribute__((ext_vector_type(8)))  __bf16;
using floatx16 = __attribute__((ext_vector_type(16))) float;

static __device__ __forceinline__ unsigned short f2bf(float f) {
    unsigned int u = __float_as_uint(f);
    u += 0x7FFFu + ((u >> 16) & 1u);          // round-to-nearest-even (finite inputs)
    return (unsigned short)(u >> 16);
}

static __device__ __forceinline__ floatx16 mfma16(bf16x8 a, bf16x8 b, floatx16 c) {
    return __builtin_amdgcn_mfma_f32_32x32x16_bf16(a, b, c, 0, 0, 0);
}

// async global->LDS DMA, 16B per lane. LDS dest = wave-uniform base + lane*16
// (our per-lane lds pointers are consecutive, so first-lane base is correct).
static __device__ __forceinline__ void gload_lds16(const void* g, void* l) {
    __builtin_amdgcn_global_load_lds(
        (const __attribute__((address_space(1))) void*)g,
        (__attribute__((address_space(3))) void*)l, 16, 0, 0);
}

// ---------------------------------------------------------------------------
// Kernel 1 (fused): blocks 0..4223  = transform x -> xt (32 b x 132 padded rows)
//                   blocks 4224..4383 = gate softmax + per-task kernel synthesis
// ---------------------------------------------------------------------------
__global__ __launch_bounds__(256) void pre_kernel(
    const float* __restrict__ x,
    const float* __restrict__ gate_w, const float* __restrict__ gate_b,
    const float* __restrict__ w5, const float* __restrict__ w3,
    const float* __restrict__ w1, const float* __restrict__ wavg3,
    const float* __restrict__ wavg5, const int* __restrict__ task_id,
    unsigned short* __restrict__ xt, unsigned short* __restrict__ wk,
    float* __restrict__ out_task)
{
    const int blk = blockIdx.x;
    const int tid = threadIdx.x;
    __shared__ float g[5][64];

    if (blk < 4224) {
        // -------- transform: one padded row (b, hp) per block --------
        const int b  = blk / 132;
        const int hp = blk - b * 132;
        const int h  = hp - 2;
        const bool vrow = (h >= 0) && (h < 128);
        unsigned short* dst_row = xt + (size_t)blk * 8448;

        for (int i = tid; i < 1056; i += 256) {      // 8 cc * 132 wp uint4 blocks
            int cc = i / 132;
            int wp = i - cc * 132;
            unsigned int pk[4] = {0u, 0u, 0u, 0u};
            if (vrow && wp >= 2 && wp < 130) {
                const float* xp = x + (((size_t)(b * 64 + cc * 8) * 128 + h) * 128 + (wp - 2));
                #pragma unroll
                for (int j = 0; j < 4; ++j) {
                    unsigned short lo = f2bf(xp[(2 * j)     * 16384]);
                    unsigned short hi = f2bf(xp[(2 * j + 1) * 16384]);
                    pk[j] = (unsigned int)lo | ((unsigned int)hi << 16);
                }
            }
            *(uint4*)(dst_row + (size_t)i * 8) = make_uint4(pk[0], pk[1], pk[2], pk[3]);
        }
    } else {
        // -------- prep: per-task 5x5 kernel synthesis --------
        const int pb = blk - 4224;
        const int t = pb >> 4;          // 0..9
        const int chunk = pb & 15;      // 0..15

        if (tid < 64) {
            float l[5];
            float m = -1e30f;
            #pragma unroll
            for (int e = 0; e < 5; ++e) {
                l[e] = gate_w[(e * 64 + tid) * 10 + t] + gate_b[e * 64 + tid];
                m = fmaxf(m, l[e]);
            }
            float s = 0.f;
            #pragma unroll
            for (int e = 0; e < 5; ++e) { l[e] = expf(l[e] - m); s += l[e]; }
            float inv = 1.f / s;
            #pragma unroll
            for (int e = 0; e < 5; ++e) g[e][tid] = l[e] * inv;
        }
        __syncthreads();

        for (int it = 0; it < 25; ++it) {
            int idx = chunk * 6400 + it * 256 + tid;
            int ci  = idx & 63;
            int o   = (idx >> 6) & 63;
            int tap = idx >> 12;               // 0..24
            int ky = tap / 5, kx = tap - ky * 5;

            float v = g[0][o] * w5[(o * 64 + ci) * 25 + tap];
            bool in3 = (ky >= 1 && ky <= 3 && kx >= 1 && kx <= 3);
            if (in3) {
                v += g[1][o] * w3[(o * 64 + ci) * 9 + (ky - 1) * 3 + (kx - 1)];
                v += g[3][o] * wavg3[o * 64 + ci] * (1.f / 9.f);
            }
            if (ky == 2 && kx == 2) v += g[2][o] * w1[o * 64 + ci];
            v += g[4][o] * wavg5[o * 64 + ci] * (1.f / 25.f);

            wk[(t * 25 + tap) * 4096 + o * 64 + ci] = f2bf(v);
        }

        if (pb == 0 && tid < 32) out_task[tid] = (float)task_id[tid];
    }
}

// ---------------------------------------------------------------------------
// Kernel 2: MFMA conv, 2 INDEPENDENT blocks/CU (natural cross-block overlap).
// Block = 256 thr (4 waves), tile = 64co x (8 rows x 64 w).
// Wave = (row-group rg: 4 rows) x (w-col wc: 32 w) x 64 co -> acc[4][2].
// LDS (single-buffered, 77,312 B -> 2 blocks/CU):
//   ibuf: 12 rows x [2 cc][68 wp][8 ci] bf16 = 26,112 B
//   wlds: [25 tap][2 cih][64 co][8 ci] bf16  = 51,200 B
// Per q (16-ci quarter): stage (DMA, exposed ~1.5k cyc) -> barrier ->
// compute (pure LDS+MFMA, ~6.5k cyc) -> barrier. The sibling block on the
// same CU runs its phases independently, so its MFMAs cover our staging
// and vice versa - no manual pipelining, no vmcnt poison, no reg spill.
// ky-reuse inner loop: one B ds_read feeds up to 8 MFMAs
// (per wave per q: 50 A + 40 B ds_read_b128 vs 200 MFMA).
// grid = 1024 (32 b * 16 ht * 2 wt), XCD-swizzled: 4 whole images per XCD;
// wt-pairs and ht-neighbors are adjacent -> halo + weights L2-local.
// ---------------------------------------------------------------------------
__global__ __launch_bounds__(256, 2) void conv_kernel(
    const unsigned short* __restrict__ xt, const unsigned short* __restrict__ wk,
    const int* __restrict__ task_id, float* __restrict__ out)
{
    __shared__ __align__(16) unsigned short ibuf[13056];  // 26,112 B
    __shared__ __align__(16) unsigned short wlds[25600];  // 51,200 B

    // XCD swizzle (1024 = 8*128, bijective): XCD k gets blocks k*128..k*128+127
    const int blk = ((blockIdx.x & 7) << 7) | (blockIdx.x >> 3);
    const int b  = blk >> 5;
    const int ht = (blk >> 1) & 15;
    const int wt = blk & 1;
    const int t  = task_id[b];

    const int tid  = threadIdx.x;
    const int lane = tid & 63;
    const int wave = tid >> 6;
    const int rg = wave >> 1;              // row group 0..1 (4 output rows each)
    const int wc = wave & 1;               // w column 0..1 (32 outputs each)
    const int lane31 = lane & 31;
    const int laneh  = lane >> 5;

    floatx16 acc[4][2];                    // [out row o][co half]
    #pragma unroll
    for (int o = 0; o < 4; ++o)
        #pragma unroll
        for (int c = 0; c < 2; ++c)
            #pragma unroll
            for (int r = 0; r < 16; ++r) acc[o][c][r] = 0.f;

    const unsigned short* wkt = wk + t * 102400;           // [25][64 co][64 ci]
    const size_t ibase0 = ((size_t)(b * 132 + ht * 8)) * 8448;
    const int wbase = wt * 64;             // wp offset of this block's w-tile

    for (int q = 0; q < 4; ++q) {
        // ---- stage input: 12 rows x 2 cc x 68 wp x 8 ci (1632 uint4) ----
        {
            const unsigned short* gs = xt + ibase0 + q * 2112 + wbase * 8;
            #pragma unroll
            for (int j = 0; j < 7; ++j) {          // 1632 = 256*6 + 96
                if (j < 6 || tid < 96) {
                    int i = j * 256 + tid;
                    int run = i / 68;              // 0..23 = r*2 + cc
                    int off = i - run * 68;
                    int r   = run >> 1;
                    int cc  = run & 1;
                    gload_lds16(gs + (size_t)r * 8448 + cc * 1056 + off * 8,
                                ibuf + (size_t)i * 8);
                }
            }
        }
        // ---- stage weights: [25 tap][2 cih][64 co][8 ci] (3200 uint4) ----
        {
            const unsigned short* gs = wkt + q * 16;
            #pragma unroll
            for (int j = 0; j < 13; ++j) {         // 3200 = 256*12 + 128
                if (j < 12 || tid < 128) {
                    int i = j * 256 + tid;
                    int tap = i >> 7;
                    int rem = i & 127;
                    int cih = rem >> 6;
                    int co  = rem & 63;
                    gload_lds16(gs + tap * 4096 + co * 64 + cih * 8,
                                wlds + (size_t)i * 8);
                }
            }
        }
        asm volatile("s_waitcnt vmcnt(0)" ::: "memory");
        __builtin_amdgcn_s_barrier();
        __builtin_amdgcn_sched_barrier(0);

        // ---- compute: pure LDS + MFMA ----
        __builtin_amdgcn_s_setprio(1);
        #pragma unroll
        for (int kx = 0; kx < 5; ++kx) {
            const unsigned short* wkx = wlds + kx * 1024 + laneh * 512 + lane31 * 8;
            const unsigned short* ibb = ibuf + laneh * 544
                                      + (wc * 32 + lane31 + kx) * 8;
            bf16x8 aF[5][2];                      // 5 ky x 2 co-halves
            #pragma unroll
            for (int ky = 0; ky < 5; ++ky) {
                const unsigned short* ap = wkx + ky * 5120;   // tap = ky*5+kx
                aF[ky][0] = *(const bf16x8*)(ap);
                aF[ky][1] = *(const bf16x8*)(ap + 256);       // +32 co
            }
            #pragma unroll
            for (int hr = 0; hr < 8; ++hr) {      // staged row rg*4 + hr
                bf16x8 bb = *(const bf16x8*)(ibb + (rg * 4 + hr) * 1088);
                #pragma unroll
                for (int ky = 0; ky < 5; ++ky) {
                    const int o = hr - ky;        // compile-time after unroll
                    if (o >= 0 && o < 4) {
                        acc[o][0] = mfma16(aF[ky][0], bb, acc[o][0]);
                        acc[o][1] = mfma16(aF[ky][1], bb, acc[o][1]);
                    }
                }
            }
        }
        __builtin_amdgcn_s_setprio(0);

        asm volatile("s_waitcnt lgkmcnt(0)" ::: "memory");
        __builtin_amdgcn_s_barrier();          // reads done before next overwrite
        __builtin_amdgcn_sched_barrier(0);
    }

    // Epilogue: C/D layout (32x32): col(w) = lane&31, row(co) = (reg&3)+8*(reg>>2)+4*(lane>>5)
    #pragma unroll
    for (int o = 0; o < 4; ++o) {
        const int h = ht * 8 + rg * 4 + o;
        const int w = wbase + wc * 32 + lane31;
        #pragma unroll
        for (int c = 0; c < 2; ++c) {
            #pragma unroll
            for (int reg = 0; reg < 16; ++reg) {
                int co = c * 32 + (reg & 3) + 8 * (reg >> 2) + 4 * laneh;
                out[((size_t)(b * 64 + co) * 128 + h) * 128 + w] = acc[o][c][reg];
            }
        }
    }
}

// ---------------------------------------------------------------------------
extern "C" void kernel_launch(void* const* d_in, const int* in_sizes, int n_in,
                              void* d_out, int out_size, void* d_ws, size_t ws_size,
                              hipStream_t stream) {
    const float* x       = (const float*)d_in[0];
    const int*   task_id = (const int*)  d_in[1];
    const float* gate_w  = (const float*)d_in[2];
    const float* gate_b  = (const float*)d_in[3];
    const float* w5      = (const float*)d_in[4];
    const float* w3      = (const float*)d_in[5];
    const float* w1      = (const float*)d_in[6];
    const float* wavg3   = (const float*)d_in[7];
    const float* wavg5   = (const float*)d_in[8];

    float* out = (float*)d_out;
    float* out_task = out + 32 * 64 * 128 * 128;   // second tuple element

    unsigned short* xt = (unsigned short*)d_ws;
    unsigned short* wk = (unsigned short*)((char*)d_ws + WK_OFFSET_BYTES);
    // requires ws_size >= 73,416,704 bytes

    pre_kernel<<<dim3(4384), dim3(256), 0, stream>>>(
        x, gate_w, gate_b, w5, w3, w1, wavg3, wavg5, task_id, xt, wk, out_task);
    conv_kernel<<<dim3(1024), dim3(256), 0, stream>>>(xt, wk, task_id, out);
}

// Round 7
// 343.439 us; speedup vs baseline: 1.0769x; 1.0000x over previous
//
#include <hip/hip_runtime.h>

// Problem: B=32, CI=64, CO=64, H=128, W=128, E=5, T=10, 5x5 SAME conv (MoDE).
// d_out = y[32*64*128*128] f32 ++ task_id[32] (as float).
//
// ws layout:
//   xt : [32 b][132 hp][8 cc][132 wp][8 ci] bf16 = 71,368,704 B
//        hp = h+2 (rows 0,1,130,131 zero), wp = w+2 (borders zero)
//   wk : [10 t][25 tap][64 co][64 ci] bf16       =  2,048,000 B
// requires ws_size >= 73,416,704 bytes.
#define WK_OFFSET_BYTES 71368704ull

using bf16x8   = __attribute__((ext_vector_type(8)))  __bf16;
using floatx16 = __attribute__((ext_vector_type(16))) float;

static __device__ __forceinline__ unsigned short f2bf(float f) {
    unsigned int u = __float_as_uint(f);
    u += 0x7FFFu + ((u >> 16) & 1u);          // round-to-nearest-even (finite inputs)
    return (unsigned short)(u >> 16);
}

static __device__ __forceinline__ floatx16 mfma16(bf16x8 a, bf16x8 b, floatx16 c) {
    return __builtin_amdgcn_mfma_f32_32x32x16_bf16(a, b, c, 0, 0, 0);
}

// async global->LDS DMA, 16B per lane. LDS dest = wave-uniform base + lane*16
// (our per-lane lds pointers are consecutive, so first-lane base is correct).
static __device__ __forceinline__ void gload_lds16(const void* g, void* l) {
    __builtin_amdgcn_global_load_lds(
        (const __attribute__((address_space(1))) void*)g,
        (__attribute__((address_space(3))) void*)l, 16, 0, 0);
}

// ---------------------------------------------------------------------------
// Kernel 1 (fused): blocks 0..4223  = transform x -> xt (32 b x 132 padded rows)
//                   blocks 4224..4383 = gate softmax + per-task kernel synthesis
// ---------------------------------------------------------------------------
__global__ __launch_bounds__(256) void pre_kernel(
    const float* __restrict__ x,
    const float* __restrict__ gate_w, const float* __restrict__ gate_b,
    const float* __restrict__ w5, const float* __restrict__ w3,
    const float* __restrict__ w1, const float* __restrict__ wavg3,
    const float* __restrict__ wavg5, const int* __restrict__ task_id,
    unsigned short* __restrict__ xt, unsigned short* __restrict__ wk,
    float* __restrict__ out_task)
{
    const int blk = blockIdx.x;
    const int tid = threadIdx.x;
    __shared__ float g[5][64];

    if (blk < 4224) {
        // -------- transform: one padded row (b, hp) per block --------
        const int b  = blk / 132;
        const int hp = blk - b * 132;
        const int h  = hp - 2;
        const bool vrow = (h >= 0) && (h < 128);
        unsigned short* dst_row = xt + (size_t)blk * 8448;

        for (int i = tid; i < 1056; i += 256) {      // 8 cc * 132 wp uint4 blocks
            int cc = i / 132;
            int wp = i - cc * 132;
            unsigned int pk[4] = {0u, 0u, 0u, 0u};
            if (vrow && wp >= 2 && wp < 130) {
                const float* xp = x + (((size_t)(b * 64 + cc * 8) * 128 + h) * 128 + (wp - 2));
                #pragma unroll
                for (int j = 0; j < 4; ++j) {
                    unsigned short lo = f2bf(xp[(2 * j)     * 16384]);
                    unsigned short hi = f2bf(xp[(2 * j + 1) * 16384]);
                    pk[j] = (unsigned int)lo | ((unsigned int)hi << 16);
                }
            }
            *(uint4*)(dst_row + (size_t)i * 8) = make_uint4(pk[0], pk[1], pk[2], pk[3]);
        }
    } else {
        // -------- prep: per-task 5x5 kernel synthesis --------
        const int pb = blk - 4224;
        const int t = pb >> 4;          // 0..9
        const int chunk = pb & 15;      // 0..15

        if (tid < 64) {
            float l[5];
            float m = -1e30f;
            #pragma unroll
            for (int e = 0; e < 5; ++e) {
                l[e] = gate_w[(e * 64 + tid) * 10 + t] + gate_b[e * 64 + tid];
                m = fmaxf(m, l[e]);
            }
            float s = 0.f;
            #pragma unroll
            for (int e = 0; e < 5; ++e) { l[e] = expf(l[e] - m); s += l[e]; }
            float inv = 1.f / s;
            #pragma unroll
            for (int e = 0; e < 5; ++e) g[e][tid] = l[e] * inv;
        }
        __syncthreads();

        for (int it = 0; it < 25; ++it) {
            int idx = chunk * 6400 + it * 256 + tid;
            int ci  = idx & 63;
            int o   = (idx >> 6) & 63;
            int tap = idx >> 12;               // 0..24
            int ky = tap / 5, kx = tap - ky * 5;

            float v = g[0][o] * w5[(o * 64 + ci) * 25 + tap];
            bool in3 = (ky >= 1 && ky <= 3 && kx >= 1 && kx <= 3);
            if (in3) {
                v += g[1][o] * w3[(o * 64 + ci) * 9 + (ky - 1) * 3 + (kx - 1)];
                v += g[3][o] * wavg3[o * 64 + ci] * (1.f / 9.f);
            }
            if (ky == 2 && kx == 2) v += g[2][o] * w1[o * 64 + ci];
            v += g[4][o] * wavg5[o * 64 + ci] * (1.f / 25.f);

            wk[(t * 25 + tap) * 4096 + o * 64 + ci] = f2bf(v);
        }

        if (pb == 0 && tid < 32) out_task[tid] = (float)task_id[tid];
    }
}

// ---------------------------------------------------------------------------
// Kernel 2: MFMA conv, 2 blocks/CU + ANTI-PHASE STAGGER.
// Identical to R6 except: one block of each co-resident pair sleeps ~16k cyc
// (half a q-phase) at start, so its stage/store bursts fall inside the
// sibling's MFMA phase (and vice versa). R6 showed co-residency alone is
// null because both blocks are phase-locked: MFMA busy == floor (43us) but
// pipes (matrix / LDS / L2-stage / HBM-store) serialize CU-wide.
// Pairing hedge: with XCD round-robin on blockIdx&7, co-residents within an
// XCD differ in m=blockIdx>>3 by 1 (slot-major) or 32 (CU-major);
// (m ^ (m>>5)) & 1 anti-phases BOTH pairings.
// Block = 256 thr (4 waves), tile = 64co x (8 rows x 64 w).
// LDS 77,312 B single-buffered: ibuf 26,112 + wlds 51,200 -> 2 blocks/CU.
// Per q: stage(DMA) -> vmcnt(0)+barrier -> pure LDS+MFMA compute -> barrier.
// ky-reuse: one B ds_read feeds up to 8 MFMAs (90 reads / 200 MFMA per wave/q).
// grid = 1024 (32 b * 16 ht * 2 wt), XCD-swizzled: 4 whole images per XCD.
// ---------------------------------------------------------------------------
__global__ __launch_bounds__(256, 2) void conv_kernel(
    const unsigned short* __restrict__ xt, const unsigned short* __restrict__ wk,
    const int* __restrict__ task_id, float* __restrict__ out)
{
    __shared__ __align__(16) unsigned short ibuf[13056];  // 26,112 B
    __shared__ __align__(16) unsigned short wlds[25600];  // 51,200 B

    // ---- anti-phase stagger (the ONE change vs R6) ----
    {
        const int m = (int)(blockIdx.x >> 3);              // XCD-local index
        if ((m ^ (m >> 5)) & 1) {
            __builtin_amdgcn_s_sleep(127);                 // ~8k cyc
            __builtin_amdgcn_s_sleep(127);                 // ~16k total (~half q-phase)
        }
    }

    // XCD swizzle (1024 = 8*128, bijective): XCD k gets blocks k*128..k*128+127
    const int blk = ((blockIdx.x & 7) << 7) | (blockIdx.x >> 3);
    const int b  = blk >> 5;
    const int ht = (blk >> 1) & 15;
    const int wt = blk & 1;
    const int t  = task_id[b];

    const int tid  = threadIdx.x;
    const int lane = tid & 63;
    const int wave = tid >> 6;
    const int rg = wave >> 1;              // row group 0..1 (4 output rows each)
    const int wc = wave & 1;               // w column 0..1 (32 outputs each)
    const int lane31 = lane & 31;
    const int laneh  = lane >> 5;

    floatx16 acc[4][2];                    // [out row o][co half]
    #pragma unroll
    for (int o = 0; o < 4; ++o)
        #pragma unroll
        for (int c = 0; c < 2; ++c)
            #pragma unroll
            for (int r = 0; r < 16; ++r) acc[o][c][r] = 0.f;

    const unsigned short* wkt = wk + t * 102400;           // [25][64 co][64 ci]
    const size_t ibase0 = ((size_t)(b * 132 + ht * 8)) * 8448;
    const int wbase = wt * 64;             // wp offset of this block's w-tile

    for (int q = 0; q < 4; ++q) {
        // ---- stage input: 12 rows x 2 cc x 68 wp x 8 ci (1632 uint4) ----
        {
            const unsigned short* gs = xt + ibase0 + q * 2112 + wbase * 8;
            #pragma unroll
            for (int j = 0; j < 7; ++j) {          // 1632 = 256*6 + 96
                if (j < 6 || tid < 96) {
                    int i = j * 256 + tid;
                    int run = i / 68;              // 0..23 = r*2 + cc
                    int off = i - run * 68;
                    int r   = run >> 1;
                    int cc  = run & 1;
                    gload_lds16(gs + (size_t)r * 8448 + cc * 1056 + off * 8,
                                ibuf + (size_t)i * 8);
                }
            }
        }
        // ---- stage weights: [25 tap][2 cih][64 co][8 ci] (3200 uint4) ----
        {
            const unsigned short* gs = wkt + q * 16;
            #pragma unroll
            for (int j = 0; j < 13; ++j) {         // 3200 = 256*12 + 128
                if (j < 12 || tid < 128) {
                    int i = j * 256 + tid;
                    int tap = i >> 7;
                    int rem = i & 127;
                    int cih = rem >> 6;
                    int co  = rem & 63;
                    gload_lds16(gs + tap * 4096 + co * 64 + cih * 8,
                                wlds + (size_t)i * 8);
                }
            }
        }
        asm volatile("s_waitcnt vmcnt(0)" ::: "memory");
        __builtin_amdgcn_s_barrier();
        __builtin_amdgcn_sched_barrier(0);

        // ---- compute: pure LDS + MFMA ----
        __builtin_amdgcn_s_setprio(1);
        #pragma unroll
        for (int kx = 0; kx < 5; ++kx) {
            const unsigned short* wkx = wlds + kx * 1024 + laneh * 512 + lane31 * 8;
            const unsigned short* ibb = ibuf + laneh * 544
                                      + (wc * 32 + lane31 + kx) * 8;
            bf16x8 aF[5][2];                      // 5 ky x 2 co-halves
            #pragma unroll
            for (int ky = 0; ky < 5; ++ky) {
                const unsigned short* ap = wkx + ky * 5120;   // tap = ky*5+kx
                aF[ky][0] = *(const bf16x8*)(ap);
                aF[ky][1] = *(const bf16x8*)(ap + 256);       // +32 co
            }
            #pragma unroll
            for (int hr = 0; hr < 8; ++hr) {      // staged row rg*4 + hr
                bf16x8 bb = *(const bf16x8*)(ibb + (rg * 4 + hr) * 1088);
                #pragma unroll
                for (int ky = 0; ky < 5; ++ky) {
                    const int o = hr - ky;        // compile-time after unroll
                    if (o >= 0 && o < 4) {
                        acc[o][0] = mfma16(aF[ky][0], bb, acc[o][0]);
                        acc[o][1] = mfma16(aF[ky][1], bb, acc[o][1]);
                    }
                }
            }
        }
        __builtin_amdgcn_s_setprio(0);

        asm volatile("s_waitcnt lgkmcnt(0)" ::: "memory");
        __builtin_amdgcn_s_barrier();          // reads done before next overwrite
        __builtin_amdgcn_sched_barrier(0);
    }

    // Epilogue: C/D layout (32x32): col(w) = lane&31, row(co) = (reg&3)+8*(reg>>2)+4*(lane>>5)
    #pragma unroll
    for (int o = 0; o < 4; ++o) {
        const int h = ht * 8 + rg * 4 + o;
        const int w = wbase + wc * 32 + lane31;
        #pragma unroll
        for (int c = 0; c < 2; ++c) {
            #pragma unroll
            for (int reg = 0; reg < 16; ++reg) {
                int co = c * 32 + (reg & 3) + 8 * (reg >> 2) + 4 * laneh;
                out[((size_t)(b * 64 + co) * 128 + h) * 128 + w] = acc[o][c][reg];
            }
        }
    }
}

// ---------------------------------------------------------------------------
extern "C" void kernel_launch(void* const* d_in, const int* in_sizes, int n_in,
                              void* d_out, int out_size, void* d_ws, size_t ws_size,
                              hipStream_t stream) {
    const float* x       = (const float*)d_in[0];
    const int*   task_id = (const int*)  d_in[1];
    const float* gate_w  = (const float*)d_in[2];
    const float* gate_b  = (const float*)d_in[3];
    const float* w5      = (const float*)d_in[4];
    const float* w3      = (const float*)d_in[5];
    const float* w1      = (const float*)d_in[6];
    const float* wavg3   = (const float*)d_in[7];
    const float* wavg5   = (const float*)d_in[8];

    float* out = (float*)d_out;
    float* out_task = out + 32 * 64 * 128 * 128;   // second tuple element

    unsigned short* xt = (unsigned short*)d_ws;
    unsigned short* wk = (unsigned short*)((char*)d_ws + WK_OFFSET_BYTES);
    // requires ws_size >= 73,416,704 bytes

    pre_kernel<<<dim3(4384), dim3(256), 0, stream>>>(
        x, gate_w, gate_b, w5, w3, w1, wavg3, wavg5, task_id, xt, wk, out_task);
    conv_kernel<<<dim3(1024), dim3(256), 0, stream>>>(xt, wk, task_id, out);
}